// Round 6
// baseline (497.580 us; speedup 1.0000x reference)
//
#include <hip/hip_runtime.h>
#include <math.h>

// Bayesian 2-layer LSTM (B=8192,T=100,I=24,H=64,H2=128) — two-kernel version.
//
// R6: W2 fragments pinned into AGPRs. R5 profile: 9150 cyc/iter/CU with the
// layer-2 weight stream (196 KB/CU/iter from L2 ~= 3500 cyc) on the critical
// path; VALU 48%, MFMA 23%. The compiler refuses to keep the 96-reg W2 array
// in registers on its own (R1/R3: scratch spill). Here each of the 24 W2
// short8 fragments is loaded once and pinned to the AGPR file via an empty
// inline asm with "+a" constraint; gfx950 MFMA reads A/B from AGPR directly
// (unified file), so the K-loop has NO global loads at all.
// Budget: 96 AGPR + ~135 arch VGPR < 256 (2 waves/SIMD) -> no spill expected.
// Tell: WRITE_SIZE stays ~bytes if pinned; tens of MB if the allocator spilled.

typedef __attribute__((ext_vector_type(8))) short short8;   // 8 bf16
typedef __attribute__((ext_vector_type(4))) float f32x4;

#define MFMA16(a, b, c) __builtin_amdgcn_mfma_f32_16x16x32_bf16((a), (b), (c), 0, 0, 0)

// ---- d_ws layout (bytes) ----
// [0, 196608)        W2S : 12288 short8 frags, idx = (kk*4+g)*512 + tid
// [196608, 245760)   W1G : 3072 short8, u = slice*256+n (slice = kk*4+quad)
// [245760, 253284)   WF  : 1881 floats: b1[256] b2[512] fc1w[1024] fc2w[64]
//                          fc1b[8] fc2b[8] ow[8] ob[1]
#define WS_W1G_OFF 196608
#define WS_WF_OFF  245760

struct SampParams {
  const float* w1i[3]; const float* w1h[3]; const float* b1[3];
  const float* w2i[3]; const float* w2h[3]; const float* b2[3];
  const float* f1w[3]; const float* f1b[3];
  const float* f2w[3]; const float* f2b[3];
  const float* ow[3];  const float* ob[3];
  short* W2S; short* W1G; float* WF;
};

struct LstmParams {
  const float* input;
  const short* W2S; const short* W1G; const float* WF;
  float* out;
};

__device__ __forceinline__ float samp(const float* const q[3], int idx) {
  return q[0][idx] + log1pf(expf(q[1][idx])) * q[2][idx];
}

__device__ __forceinline__ short f2bf(float f) {
  unsigned u = __float_as_uint(f);
  unsigned r = (u + 0x7FFFu + ((u >> 16) & 1u)) >> 16;   // RNE
  return (short)r;
}

__device__ __forceinline__ float sigf(float x) {
  return __builtin_amdgcn_rcpf(1.0f + __builtin_amdgcn_exp2f(-1.44269504f * x));
}
__device__ __forceinline__ float tanhf_(float x) {
  return 1.0f - 2.0f * __builtin_amdgcn_rcpf(1.0f + __builtin_amdgcn_exp2f(2.88539008f * x));
}

// ---------------- kernel 1: sample all weights into d_ws ----------------
__global__ __launch_bounds__(256) void sample_kernel(SampParams p)
{
  int i = blockIdx.x * 256 + threadIdx.x;
  if (i < 12288) {
    int tid = i & 511, gg = (i >> 9) & 3, kk = i >> 11;
    int quad = (tid >> 4) & 3, col = tid & 15, v0 = (tid >> 6) * 16;
    int c = gg * 128 + v0 + col;
    short8 v;
#pragma unroll
    for (int j = 0; j < 8; ++j) {
      int k = kk * 32 + quad * 8 + j;
      float x = (k < 64) ? samp(p.w2i, k * 512 + c) : samp(p.w2h, (k - 64) * 512 + c);
      v[j] = f2bf(x);
    }
    *(short8*)&p.W2S[i * 8] = v;
  } else if (i < 15360) {
    int u = i - 12288;
    int slice = u >> 8, n = u & 255;
    int k0 = (slice >> 2) * 32 + (slice & 3) * 8;
    short8 v;
#pragma unroll
    for (int j = 0; j < 8; ++j) {
      int k = k0 + j;
      float x = 0.0f;
      if (k < 24)       x = samp(p.w1i, k * 256 + n);
      else if (k >= 32) x = samp(p.w1h, (k - 32) * 256 + n);
      v[j] = f2bf(x);
    }
    *(short8*)&p.W1G[u * 8] = v;
  } else if (i < 17241) {
    int u = i - 15360;
    float x;
    if (u < 256)       x = samp(p.b1,  u);
    else if (u < 768)  x = samp(p.b2,  u - 256);
    else if (u < 1792) x = samp(p.f1w, u - 768);
    else if (u < 1856) x = samp(p.f2w, u - 1792);
    else if (u < 1864) x = samp(p.f1b, u - 1856);
    else if (u < 1872) x = samp(p.f2b, u - 1864);
    else if (u < 1880) x = samp(p.ow,  u - 1872);
    else               x = samp(p.ob,  0);
    p.WF[u] = x;
  }
}

// ---------------- kernel 2: fused 2-layer LSTM + head ----------------
// LDS pool:
//   [0,49152)      W1L : W1cat bf16 (3072 short8)
//   [49152,55808)  A1  : 32 x 104 shorts [x(24)|pad(8)|h1(64)]
//   [55808,64512)  A2  : 32 x 136 shorts [h2(128)|pad]
// Head phase aliases [0,...) : H2 32x132 f32, FC1W, FC2W, FB1/FB2/OW/OB, X1, X2

__global__ __launch_bounds__(512, 2)
void blstm_kernel(LstmParams p)
{
  __shared__ __align__(16) unsigned char pool[64512];
  short* const W1L = (short*)pool;
  short* const A1  = (short*)(pool + 49152);
  short* const A2  = (short*)(pool + 55808);

  const int tid  = threadIdx.x;
  const int w    = tid >> 6;
  const int l    = tid & 63;
  const int quad = l >> 4;
  const int col  = l & 15;
  const int b0   = blockIdx.x * 32;

  const int wq = w & 3;             // layer1: n-group
  const int mh = w >> 2;            // layer1: m-half
  const int v0 = w * 16;            // layer2: unit base

  // ---- load W2 fragments once; pin them into AGPRs ----
  const short8* const W2v = (const short8*)p.W2S;
  short8 W2a[6][4];
#pragma unroll
  for (int kk = 0; kk < 6; ++kk)
#pragma unroll
    for (int g = 0; g < 4; ++g)
      W2a[kk][g] = W2v[(kk * 4 + g) * 512 + tid];
#pragma unroll
  for (int kk = 0; kk < 6; ++kk)
#pragma unroll
    for (int g = 0; g < 4; ++g)
      __asm__ volatile("" : "+a"(W2a[kk][g]));   // force AGPR residency

  // W1 global -> LDS (48 KB)
#pragma unroll
  for (int r = 0; r < 6; ++r) {
    short8 v = *(const short8*)&p.W1G[(r * 512 + tid) * 8];
    *(short8*)&W1L[(r * 512 + tid) * 8] = v;
  }

  float b1v[4], b2v[4];
#pragma unroll
  for (int g = 0; g < 4; ++g) b1v[g] = p.WF[g * 64 + wq * 16 + col];
#pragma unroll
  for (int g = 0; g < 4; ++g) b2v[g] = p.WF[256 + g * 128 + v0 + col];

  for (int i = tid; i < 3328; i += 512) A1[i] = 0;
  for (int i = tid; i < 4352; i += 512) A2[i] = 0;
  __syncthreads();

  // x_0 -> A1; hoisted per-thread x addressing
  int xr = 0, xi = 0;
  const float* xptr = p.input;
  if (tid < 384) {
    int e = tid * 2; xr = e / 24; xi = e - xr * 24;
    const float* base = p.input + (size_t)(b0 + xr) * 2400 + xi;
    float2 xv = *(const float2*)base;
    unsigned pk = (unsigned)(unsigned short)f2bf(xv.x)
                | ((unsigned)(unsigned short)f2bf(xv.y) << 16);
    *(unsigned*)&A1[xr * 104 + xi] = pk;
    xptr = base + 24;                 // -> x_1
  }
  __syncthreads();

  f32x4 c1 = {0.f, 0.f, 0.f, 0.f};
  f32x4 c2[2]; c2[0] = c1; c2[1] = c1;
  float hf2[2][4];

  const int a1rd = (mh * 16 + col) * 104;

  // Iteration j: computes h1_j (layer1 on [x_j|h1_{j-1}]) and h2_{j-1}
  // (layer2 on [h1_{j-1}|h2_{j-2}]). l2 state update skipped at j=0.
  for (int j = 0; j <= 100; ++j) {
    const bool do_x = (j <= 98) && (tid < 384);
    float2 xv;
    if (do_x) xv = *(const float2*)xptr;   // x_{j+1}

    // ---- layer 1 matmul: gates1_j ----
    short8 aA0 = *(const short8*)&A1[a1rd +      quad * 8];
    short8 aA1 = *(const short8*)&A1[a1rd + 32 + quad * 8];
    short8 aA2 = *(const short8*)&A1[a1rd + 64 + quad * 8];
    f32x4 g1[4];
#pragma unroll
    for (int g = 0; g < 4; ++g) {
      f32x4 acc = (f32x4){b1v[g], b1v[g], b1v[g], b1v[g]};
      acc = MFMA16(aA0, *(const short8*)&W1L[(((0 * 4 + quad) << 8) + g * 64 + wq * 16 + col) * 8], acc);
      acc = MFMA16(aA1, *(const short8*)&W1L[(((1 * 4 + quad) << 8) + g * 64 + wq * 16 + col) * 8], acc);
      acc = MFMA16(aA2, *(const short8*)&W1L[(((2 * 4 + quad) << 8) + g * 64 + wq * 16 + col) * 8], acc);
      g1[g] = acc;
    }

    // ---- layer 2 matmul: gates2_{j-1}; W2 read from AGPRs ----
    f32x4 g2[2][4];
#pragma unroll
    for (int g = 0; g < 4; ++g) {
      g2[0][g] = (f32x4){b2v[g], b2v[g], b2v[g], b2v[g]};
      g2[1][g] = g2[0][g];
    }
#pragma unroll
    for (int kk = 0; kk < 6; ++kk) {
      short8 a0, a1f;
      if (kk < 2) {
        a0  = *(const short8*)&A1[      col  * 104 + 32 + kk * 32 + quad * 8];
        a1f = *(const short8*)&A1[(16 + col) * 104 + 32 + kk * 32 + quad * 8];
      } else {
        int o = (kk - 2) * 32 + quad * 8;
        a0  = *(const short8*)&A2[      col  * 136 + o];
        a1f = *(const short8*)&A2[(16 + col) * 136 + o];
      }
      g2[0][0] = MFMA16(a0,  W2a[kk][0], g2[0][0]);
      g2[0][1] = MFMA16(a0,  W2a[kk][1], g2[0][1]);
      g2[0][2] = MFMA16(a0,  W2a[kk][2], g2[0][2]);
      g2[0][3] = MFMA16(a0,  W2a[kk][3], g2[0][3]);
      g2[1][0] = MFMA16(a1f, W2a[kk][0], g2[1][0]);
      g2[1][1] = MFMA16(a1f, W2a[kk][1], g2[1][1]);
      g2[1][2] = MFMA16(a1f, W2a[kk][2], g2[1][2]);
      g2[1][3] = MFMA16(a1f, W2a[kk][3], g2[1][3]);
    }

    // ---- pointwise layer 1 -> h1_j ----
    short hb1[4];
#pragma unroll
    for (int i = 0; i < 4; ++i) {
      float iv = sigf(g1[0][i]);
      float fv = sigf(g1[1][i]);
      float gv = tanhf_(g1[2][i]);
      float ov = sigf(g1[3][i]);
      float cn = fv * c1[i] + iv * gv;
      c1[i] = cn;
      hb1[i] = f2bf(ov * tanhf_(cn));
    }

    // ---- pointwise layer 2 -> h2_{j-1} (skip j=0) ----
    short hb2[2][4];
    if (j) {
#pragma unroll
      for (int mi = 0; mi < 2; ++mi)
#pragma unroll
        for (int i = 0; i < 4; ++i) {
          float iv = sigf(g2[mi][0][i]);
          float fv = sigf(g2[mi][1][i]);
          float gv = tanhf_(g2[mi][2][i]);
          float ov = sigf(g2[mi][3][i]);
          float cn = fv * c2[mi][i] + iv * gv;
          c2[mi][i] = cn;
          float hv = ov * tanhf_(cn);
          hf2[mi][i] = hv;
          hb2[mi][i] = f2bf(hv);
        }
    }
    __syncthreads();   // B1: all reads of A1/A2 done

    // ---- write segment: h1_j, h2_{j-1}, x_{j+1} ----
    {
      int u = wq * 16 + col;
#pragma unroll
      for (int i = 0; i < 4; ++i) {
        int row = mh * 16 + quad * 4 + i;
        A1[row * 104 + 32 + u] = hb1[i];
      }
      if (do_x) {
        unsigned pk = (unsigned)(unsigned short)f2bf(xv.x)
                    | ((unsigned)(unsigned short)f2bf(xv.y) << 16);
        *(unsigned*)&A1[xr * 104 + xi] = pk;
      }
      if (j) {
        int u2 = v0 + col;
#pragma unroll
        for (int mi = 0; mi < 2; ++mi)
#pragma unroll
          for (int i = 0; i < 4; ++i) {
            int row = mi * 16 + quad * 4 + i;
            A2[row * 136 + u2] = hb2[mi][i];
          }
      }
    }
    __syncthreads();   // B2: new state visible
    xptr += 24;
  }

  // ---- head (fp32), aliased over W1L region ----
  float* const H2   = (float*)pool;                 // 32 x 132
  float* const FC1W = (float*)(pool + 16896);
  float* const FC2W = (float*)(pool + 20992);
  float* const FB1  = (float*)(pool + 21248);
  float* const FB2  = (float*)(pool + 21280);
  float* const OWp  = (float*)(pool + 21312);
  float* const OBp  = (float*)(pool + 21344);
  float* const X1   = (float*)(pool + 21376);
  float* const X2   = (float*)(pool + 22400);

  {
    int u2 = v0 + col;
#pragma unroll
    for (int mi = 0; mi < 2; ++mi)
#pragma unroll
      for (int i = 0; i < 4; ++i) {
        int row = mi * 16 + quad * 4 + i;
        H2[row * 132 + u2] = hf2[mi][i];   // h2_99
      }
  }
  for (int i = tid; i < 1024; i += 512) FC1W[i] = p.WF[768 + i];
  if (tid < 64)               FC2W[tid]     = p.WF[1792 + tid];
  if (tid >= 64 && tid < 72)  FB1[tid - 64] = p.WF[1856 + tid - 64];
  if (tid >= 72 && tid < 80)  FB2[tid - 72] = p.WF[1864 + tid - 72];
  if (tid >= 80 && tid < 88)  OWp[tid - 80] = p.WF[1872 + tid - 80];
  if (tid == 88)              OBp[0]        = p.WF[1880];
  __syncthreads();

  if (tid < 256) {
    int row = tid >> 3, o = tid & 7;
    float s = FB1[o];
#pragma unroll 8
    for (int k = 0; k < 128; ++k) s += H2[row * 132 + k] * FC1W[o * 128 + k];
    X1[tid] = fmaxf(s, 0.0f);
  }
  __syncthreads();
  if (tid < 256) {
    int row = tid >> 3, o = tid & 7;
    float s = FB2[o];
#pragma unroll
    for (int k = 0; k < 8; ++k) s += X1[row * 8 + k] * FC2W[o * 8 + k];
    X2[tid] = fmaxf(s, 0.0f);
  }
  __syncthreads();
  if (tid < 32) {
    float s = OBp[0];
#pragma unroll
    for (int k = 0; k < 8; ++k) s += X2[tid * 8 + k] * OWp[k];
    p.out[b0 + tid] = s;
  }
}

extern "C" void kernel_launch(void* const* d_in, const int* in_sizes, int n_in,
                              void* d_out, int out_size, void* d_ws, size_t ws_size,
                              hipStream_t stream)
{
  (void)in_sizes; (void)n_in; (void)ws_size; (void)out_size;

  SampParams sp;
  const float** grp[12] = { sp.w1i, sp.w1h, sp.b1, sp.w2i, sp.w2h, sp.b2,
                            sp.f1w, sp.f1b, sp.f2w, sp.f2b, sp.ow, sp.ob };
  int idx = 1;
  for (int t = 0; t < 12; ++t)
    for (int j = 0; j < 3; ++j)
      grp[t][j] = (const float*)d_in[idx++];
  sp.W2S = (short*)d_ws;
  sp.W1G = (short*)((char*)d_ws + WS_W1G_OFF);
  sp.WF  = (float*)((char*)d_ws + WS_WF_OFF);

  LstmParams bp;
  bp.input = (const float*)d_in[0];
  bp.W2S = (const short*)d_ws;
  bp.W1G = (const short*)((char*)d_ws + WS_W1G_OFF);
  bp.WF  = (const float*)((char*)d_ws + WS_WF_OFF);
  bp.out = (float*)d_out;

  sample_kernel<<<dim3(68), dim3(256), 0, stream>>>(sp);
  blstm_kernel<<<dim3(256), dim3(512), 0, stream>>>(bp);
}